// Round 6
// baseline (350.871 us; speedup 1.0000x reference)
//
#include <hip/hip_runtime.h>
#include <hip/hip_bf16.h>
#include <stdint.h>

#define NDIM 4096
#define BM 128
#define BN 128
#define BK 64            // 8 chunks of 8 bf16 (16B vaults) per row
#define CHUNK 16         // split-K: max BK64-iters per block

typedef __attribute__((ext_vector_type(8))) short bf16x8;
typedef __attribute__((ext_vector_type(8))) unsigned short u16x8;
typedef __attribute__((ext_vector_type(4))) float f32x4;

__device__ __forceinline__ unsigned short f2bf(float f) {
    union { float f; uint32_t u; } v; v.f = f;
    uint32_t u = v.u;
    u += 0x7FFFu + ((u >> 16) & 1u);   // round-to-nearest-even
    return (unsigned short)(u >> 16);
}

// --- Fused prep kernel ---
// blocks [0,4096):      A row b -> triu-masked bf16 (16 elems/thread, ILP=4)
// blocks [4096,8192):   B -> triu-masked bf16 transposed Bt[c][k], 2 sub-tiles (64k x 32c)
// blocks [8192,8492):   zero the 300 multi-split C tiles (bj-bi >= 8) for atomics
__global__ __launch_bounds__(256) void prep_kernel(const float* __restrict__ A,
                                                   const float* __restrict__ B,
                                                   unsigned short* __restrict__ Abf,
                                                   unsigned short* __restrict__ Bt,
                                                   float* __restrict__ C) {
    __shared__ float lds[32 * 65];
    const int b   = blockIdx.x;
    const int tid = threadIdx.x;

    if (b < 4096) {
        // ---- A convert: block = one row; 16 elems/thread ----
        const int row = b;
        const int col0 = tid * 16;
        const float* src = A + (size_t)row * NDIM + col0;
        f32x4 v0 = __builtin_nontemporal_load((const f32x4*)(src));
        f32x4 v1 = __builtin_nontemporal_load((const f32x4*)(src + 4));
        f32x4 v2 = __builtin_nontemporal_load((const f32x4*)(src + 8));
        f32x4 v3 = __builtin_nontemporal_load((const f32x4*)(src + 12));
        u16x8 o0, o1;
        #pragma unroll
        for (int j = 0; j < 4; ++j) {
            o0[j]     = (col0 + j      >= row) ? f2bf(v0[j]) : (unsigned short)0;
            o0[j + 4] = (col0 + 4 + j  >= row) ? f2bf(v1[j]) : (unsigned short)0;
            o1[j]     = (col0 + 8 + j  >= row) ? f2bf(v2[j]) : (unsigned short)0;
            o1[j + 4] = (col0 + 12 + j >= row) ? f2bf(v3[j]) : (unsigned short)0;
        }
        unsigned short* dst = Abf + (size_t)row * NDIM + col0;
        *(u16x8*)(dst)     = o0;
        *(u16x8*)(dst + 8) = o1;
    } else if (b < 8192) {
        // ---- B transpose+convert: 2 sub-tiles of 64k x 32c ----
        int tb = b - 4096;
        int k0 = (tb >> 6) * 64;           // 64 k-groups
        int cp = (tb & 63) * 64;           // 64 c-pair groups
        #pragma unroll
        for (int s = 0; s < 2; ++s) {
            int c0s = cp + s * 32;
            #pragma unroll
            for (int p = 0; p < 2; ++p) {
                int kr = p * 32 + (tid >> 3);
                int cc = (tid & 7) * 4;
                f32x4 v = __builtin_nontemporal_load(
                    (const f32x4*)(B + (size_t)(k0 + kr) * NDIM + c0s + cc));
                lds[(cc + 0) * 65 + kr] = v.x;
                lds[(cc + 1) * 65 + kr] = v.y;
                lds[(cc + 2) * 65 + kr] = v.z;
                lds[(cc + 3) * 65 + kr] = v.w;
            }
            __syncthreads();
            int c  = tid >> 3;
            int ks = (tid & 7) * 8;
            u16x8 o;
            #pragma unroll
            for (int j = 0; j < 8; ++j) {
                float f = lds[c * 65 + ks + j];
                o[j] = (k0 + ks + j <= c0s + c) ? f2bf(f) : (unsigned short)0;
            }
            *(u16x8*)(Bt + (size_t)(c0s + c) * NDIM + k0 + ks) = o;
            __syncthreads();
        }
    } else {
        // ---- zero multi-split tiles (bj >= bi+8): atomics accumulate into these ----
        int t = b - 8192;                  // 0..299
        int bi = 0;
        while (t >= 24 - bi) { t -= 24 - bi; ++bi; }
        int bj = bi + 8 + t;
        float* Z = C + (size_t)(bi * BM) * NDIM + bj * BN;
        f32x4 z = {0.f, 0.f, 0.f, 0.f};
        #pragma unroll
        for (int q = 0; q < 16; ++q) {
            int off = (q * 256 + tid) * 4;
            int rr = off >> 7, cc = off & 127;
            __builtin_nontemporal_store(z, (f32x4*)(Z + (size_t)rr * NDIM + cc));
        }
    }
}

// --- Triangular bf16 MFMA GEMM, split-K (chunk <= 16 BK64-iters), R5 core ---
// 1000 blocks, d = bj-bi descending. XOR-swizzled LDS (0 conflicts, R5-verified),
// depth-2 VGPR prefetch. d<8: plain NT stores; d>=8: atomicAdd into pre-zeroed C.
__global__ __launch_bounds__(256, 4) void trigemm_kernel(
        const unsigned short* __restrict__ Abf,
        const unsigned short* __restrict__ Bt,
        float* __restrict__ C) {
    // decode blockIdx -> (d, bi, split); d descending (longest tiles first)
    int rem = blockIdx.x;
    int d = 31, nsplit = 4;
    for (;; --d) {
        nsplit = (d + 8) >> 3;             // ceil((d+1)/8) = chunks of 16 BK64-iters
        int cnt = (32 - d) * nsplit;
        if (rem < cnt) break;
        rem -= cnt;
    }
    const int bi = rem / nsplit;
    const int split = rem - bi * nsplit;
    const int bj = bi + d;

    __shared__ unsigned short As[BM * BK];   // 16 KB
    __shared__ unsigned short Bs[BN * BK];   // 16 KB

    const int tid  = threadIdx.x;
    const int wave = tid >> 6, lane = tid & 63;
    const int wm = wave >> 1, wn = wave & 1;
    const int m_l = lane & 15, kh = lane >> 4;
    const int ml7 = m_l & 7;

    f32x4 acc[4][4] = {};

    const int i0 = bi * BM, j0 = bj * BN;
    const int kiters = (d + 1) * 2;          // total BK64 steps for the tile (even)
    const int it0 = split * CHUNK;
    int nit = kiters - it0; if (nit > CHUNK) nit = CHUNK;   // even, >= 2
    const int k_start = i0 + it0 * BK;

    const unsigned short* Ar = Abf + (size_t)i0 * NDIM;
    const unsigned short* Br = Bt  + (size_t)j0 * NDIM;

    // staging map: pass p covers row r0+32p, chunk kc (16B); xor depends only on r0&7
    const int r0 = tid >> 3, kc = tid & 7;
    const int woff = r0 * BK + ((kc ^ (r0 & 7)) * 8);       // LDS short idx, + p*2048
    const size_t g0 = (size_t)r0 * NDIM + kc * 8;

    u16x8 a0_0, a0_1, a0_2, a0_3, b0_0, b0_1, b0_2, b0_3;
    u16x8 a1_0, a1_1, a1_2, a1_3, b1_0, b1_1, b1_2, b1_3;

#define LOAD_STAGE(AN, BN_, koff) do {                                          \
        const size_t _g = g0 + (size_t)(koff);                                  \
        AN##_0 = *(const u16x8*)(Ar + _g);                                      \
        AN##_1 = *(const u16x8*)(Ar + _g + (size_t)32 * NDIM);                  \
        AN##_2 = *(const u16x8*)(Ar + _g + (size_t)64 * NDIM);                  \
        AN##_3 = *(const u16x8*)(Ar + _g + (size_t)96 * NDIM);                  \
        BN_##_0 = *(const u16x8*)(Br + _g);                                     \
        BN_##_1 = *(const u16x8*)(Br + _g + (size_t)32 * NDIM);                 \
        BN_##_2 = *(const u16x8*)(Br + _g + (size_t)64 * NDIM);                 \
        BN_##_3 = *(const u16x8*)(Br + _g + (size_t)96 * NDIM);                 \
    } while (0)

#define WRITE_STAGE(AN, BN_) do {                                               \
        *(u16x8*)&As[woff         ] = AN##_0;                                   \
        *(u16x8*)&As[woff + 1*2048] = AN##_1;                                   \
        *(u16x8*)&As[woff + 2*2048] = AN##_2;                                   \
        *(u16x8*)&As[woff + 3*2048] = AN##_3;                                   \
        *(u16x8*)&Bs[woff         ] = BN_##_0;                                  \
        *(u16x8*)&Bs[woff + 1*2048] = BN_##_1;                                  \
        *(u16x8*)&Bs[woff + 2*2048] = BN_##_2;                                  \
        *(u16x8*)&Bs[woff + 3*2048] = BN_##_3;                                  \
    } while (0)

#define COMPUTE() do {                                                          \
        _Pragma("unroll")                                                       \
        for (int s = 0; s < 2; ++s) {                                           \
            const int xk = ((s * 4 + kh) ^ ml7) * 8;                            \
            bf16x8 bfr[4], afr[4];                                              \
            _Pragma("unroll")                                                   \
            for (int nt = 0; nt < 4; ++nt)                                      \
                bfr[nt] = *(const bf16x8*)&Bs[(wn*64 + nt*16 + m_l)*BK + xk];   \
            _Pragma("unroll")                                                   \
            for (int mt = 0; mt < 4; ++mt)                                      \
                afr[mt] = *(const bf16x8*)&As[(wm*64 + mt*16 + m_l)*BK + xk];   \
            _Pragma("unroll")                                                   \
            for (int mt = 0; mt < 4; ++mt)                                      \
                _Pragma("unroll")                                               \
                for (int nt = 0; nt < 4; ++nt)                                  \
                    acc[mt][nt] = __builtin_amdgcn_mfma_f32_16x16x32_bf16(      \
                        afr[mt], bfr[nt], acc[mt][nt], 0, 0, 0);                \
        }                                                                       \
    } while (0)

    LOAD_STAGE(a0, b0, k_start);
    LOAD_STAGE(a1, b1, k_start + BK);

    for (int it = 0; it < nit; it += 2) {
        WRITE_STAGE(a0, b0);                 // vmcnt wait: loads issued 1 body ago
        if (it + 2 < nit) LOAD_STAGE(a0, b0, k_start + (it + 2) * BK);
        __syncthreads();
        COMPUTE();
        __syncthreads();
        WRITE_STAGE(a1, b1);
        if (it + 3 < nit) LOAD_STAGE(a1, b1, k_start + (it + 3) * BK);
        __syncthreads();
        COMPUTE();
        __syncthreads();
    }
#undef LOAD_STAGE
#undef WRITE_STAGE
#undef COMPUTE

    // Epilogue: C/D layout col=lane&15, row=(lane>>4)*4+reg (m89/m91-verified).
    float* Cbase = C + (size_t)i0 * NDIM + j0;
    const bool single = (nsplit == 1);
    #pragma unroll
    for (int mt = 0; mt < 4; ++mt) {
        #pragma unroll
        for (int nt = 0; nt < 4; ++nt) {
            #pragma unroll
            for (int r = 0; r < 4; ++r) {
                int row = wm * 64 + mt * 16 + kh * 4 + r;
                int col = wn * 64 + nt * 16 + m_l;
                float* p = Cbase + (size_t)row * NDIM + col;
                if (single) __builtin_nontemporal_store(acc[mt][nt][r], p);
                else        atomicAdd(p, acc[mt][nt][r]);   // tile pre-zeroed in prep
            }
        }
    }
    // Mirror lower tile (bj,bi) zero-fill, once per tile (split==0)
    if (split == 0 && bi != bj) {
        float* Z = C + (size_t)j0 * NDIM + i0;
        f32x4 z = {0.f, 0.f, 0.f, 0.f};
        #pragma unroll
        for (int t = 0; t < 16; ++t) {
            int off = (t * 256 + tid) * 4;
            int rr = off >> 7, cc = off & 127;
            __builtin_nontemporal_store(z, (f32x4*)(Z + (size_t)rr * NDIM + cc));
        }
    }
}

extern "C" void kernel_launch(void* const* d_in, const int* in_sizes, int n_in,
                              void* d_out, int out_size, void* d_ws, size_t ws_size,
                              hipStream_t stream) {
    const float* A = (const float*)d_in[0];
    const float* B = (const float*)d_in[1];
    float* C = (float*)d_out;

    unsigned short* Abf = (unsigned short*)d_ws;                   // 32 MB
    unsigned short* Bt  = Abf + (size_t)NDIM * NDIM;               // 32 MB

    // prep: A-convert (4096) + B-transpose (4096) + multi-split C-tile zero (300)
    prep_kernel<<<8492, 256, 0, stream>>>(A, B, Abf, Bt, C);
    // split-K triangular GEMM: 1000 chunks of <=16 BK64-iters
    trigemm_kernel<<<1000, 256, 0, stream>>>(Abf, Bt, C);
}